// Round 7
// baseline (272.065 us; speedup 1.0000x reference)
//
#include <hip/hip_runtime.h>
#include <math.h>

// Sizes fixed by the problem.
#define BB 8
#define HH 256
#define WW 256
#define CC 64
// modes: kx in {0..31} u {224..255} (64 total), ky in {0..31}

__device__ inline void cmac(float2& a, float tx, float ty, float2 v) {
    a.x += tx * v.x - ty * v.y;
    a.y += tx * v.y + ty * v.x;
}
__device__ inline void fma4(float4& a, float s, float4 v) {
    a.x += s * v.x; a.y += s * v.y; a.z += s * v.z; a.w += s * v.w;
}

// ---------------------------------------------------------------------------
// K0: all twiddle tables (one kernel, 128 blocks x 256).
// Tf[x][j]  = e^{-2pi i kxa(j) x/256}                       (fwd x-DFT)
// Ti[j][x]  = (2/65536) e^{+2pi i kxa(j) x/256}             (inv x-DFT)
// Ty[y'][par*32+cs*16+m]: cs=0 -> cos(2pi ky y'/256), cs=1 -> -sin(...),
//                         ky = 2m+par                        (fwd y-DFT)
// T2[(pi*32+j)*128+p]: j=2m+ri; ri=0 -> cos(2pi ky p/256), ri=1 -> -sin(...),
//                         ky = 2m+pi                         (inv y-DFT)
// kxa(j) = j (j<32) else j+192.  parity(kxa(j)) == parity(j).
// ---------------------------------------------------------------------------
__global__ __launch_bounds__(256) void k_tw(float2* __restrict__ Tf,
                                            float2* __restrict__ Ti,
                                            float* __restrict__ Ty,
                                            float* __restrict__ T2) {
    int e = blockIdx.x * 256 + threadIdx.x;   // 0..32767
    if (e < 16384) {
        int x = e >> 6;
        int j = e & 63;
        int kxa = j + ((j >> 5) * 192);
        int tt = (kxa * x) & 255;
        float ang = (float)tt * (6.283185307179586f / 256.0f);
        float s, c;
        sincosf(ang, &s, &c);
        Tf[(size_t)x * 64 + j] = make_float2(c, -s);
        const float k = 2.0f / 65536.0f;
        Ti[(size_t)j * 256 + x] = make_float2(c * k, s * k);
    } else {
        int f = e - 16384;
        if (f < 8192) {
            int yp = f >> 6;
            int col = f & 63;
            int par = (col >> 5) & 1;
            int cs = (col >> 4) & 1;
            int m = col & 15;
            int ky = 2 * m + par;
            int tt = (ky * yp) & 255;
            float ang = (float)tt * (6.283185307179586f / 256.0f);
            float s, c;
            sincosf(ang, &s, &c);
            Ty[f] = cs ? -s : c;
        } else {
            int g = f - 8192;
            int pi = g >> 12;
            int j = (g >> 7) & 31;
            int p = g & 127;
            int m = j >> 1, ri = j & 1;
            int ky = 2 * m + pi;
            int tt = (ky * p) & 255;
            float ang = (float)tt * (6.283185307179586f / 256.0f);
            float s, c;
            sincosf(ang, &s, &c);
            T2[g] = ri ? -s : c;
        }
    }
}

// ---------------------------------------------------------------------------
// K1 (GEMM form, R_i=8): V[b][x][ky][i] = sum_{y'<128} Ty[y'][ky-col] *
//                 (u[y'] + (-1)^ky u[y'+128])[i]
// grid = B*H (one (b,x) row), 128 threads (2 waves).
// thread: w = t>>3 (16 groups: p = w&1, kyq = w>>1 -> m = 2kyq, 2kyq+1),
//         i8 = (t&7)*8 (8 channels).
// Per y2: 2x b64 (T broadcast) + 2x b128 (u plane) = 48 B -> 32 FMA.
// acc = 32 floats; ~110 VGPR under (128,3) cap. LDS 25.5 KB.
// ---------------------------------------------------------------------------
__global__ __launch_bounds__(128, 3) void k_fwd_y(const float* __restrict__ u,
                                                  const float* __restrict__ Ty,
                                                  float2* __restrict__ V) {
    __shared__ float ue[32 * 68];
    __shared__ float uo[32 * 68];
    __shared__ float Tt[32 * 68];

    int t = threadIdx.x;
    int b = blockIdx.x >> 8;
    int x = blockIdx.x & 255;
    int i8 = (t & 7) * 8;
    int w = t >> 3;      // 0..15
    int p = w & 1;
    int kyq = w >> 1;    // 0..7
    int yy = t >> 2;     // 0..31
    int c0 = (t & 3) * 16;

    const float* ub = u + ((size_t)(b * HH + x)) * (WW * CC);
    const float* uplane = p ? uo : ue;

    float4 A0r = {0,0,0,0}, A0i = {0,0,0,0};   // m0, i8+0..3
    float4 B0r = {0,0,0,0}, B0i = {0,0,0,0};   // m0, i8+4..7
    float4 A1r = {0,0,0,0}, A1i = {0,0,0,0};   // m1, i8+0..3
    float4 B1r = {0,0,0,0}, B1i = {0,0,0,0};   // m1, i8+4..7

    for (int yt = 0; yt < 4; ++yt) {
        const float* plo = ub + (size_t)(yt * 32 + yy) * CC + c0;
        const float* phi = plo + 128 * CC;
        float4 l0 = *(const float4*)(plo);
        float4 l1 = *(const float4*)(plo + 4);
        float4 l2 = *(const float4*)(plo + 8);
        float4 l3 = *(const float4*)(plo + 12);
        float4 h0 = *(const float4*)(phi);
        float4 h1 = *(const float4*)(phi + 4);
        float4 h2 = *(const float4*)(phi + 8);
        float4 h3 = *(const float4*)(phi + 12);
        const float* tsrc = Ty + (size_t)(yt * 32 + yy) * 64 + c0;
        float4 t0 = *(const float4*)(tsrc);
        float4 t1 = *(const float4*)(tsrc + 4);
        float4 t2 = *(const float4*)(tsrc + 8);
        float4 t3 = *(const float4*)(tsrc + 12);

        __syncthreads();   // previous tile's LDS reads complete
        int wb = yy * 68 + c0;
        *(float4*)(ue + wb)      = make_float4(l0.x+h0.x, l0.y+h0.y, l0.z+h0.z, l0.w+h0.w);
        *(float4*)(ue + wb + 4)  = make_float4(l1.x+h1.x, l1.y+h1.y, l1.z+h1.z, l1.w+h1.w);
        *(float4*)(ue + wb + 8)  = make_float4(l2.x+h2.x, l2.y+h2.y, l2.z+h2.z, l2.w+h2.w);
        *(float4*)(ue + wb + 12) = make_float4(l3.x+h3.x, l3.y+h3.y, l3.z+h3.z, l3.w+h3.w);
        *(float4*)(uo + wb)      = make_float4(l0.x-h0.x, l0.y-h0.y, l0.z-h0.z, l0.w-h0.w);
        *(float4*)(uo + wb + 4)  = make_float4(l1.x-h1.x, l1.y-h1.y, l1.z-h1.z, l1.w-h1.w);
        *(float4*)(uo + wb + 8)  = make_float4(l2.x-h2.x, l2.y-h2.y, l2.z-h2.z, l2.w-h2.w);
        *(float4*)(uo + wb + 12) = make_float4(l3.x-h3.x, l3.y-h3.y, l3.z-h3.z, l3.w-h3.w);
        *(float4*)(Tt + wb)      = t0;
        *(float4*)(Tt + wb + 4)  = t1;
        *(float4*)(Tt + wb + 8)  = t2;
        *(float4*)(Tt + wb + 12) = t3;
        __syncthreads();

        #pragma unroll
        for (int y2 = 0; y2 < 32; ++y2) {
            const float* tb = Tt + y2 * 68 + p * 32 + kyq * 2;
            float2 cp = *(const float2*)(tb);        // cos  m0,m1
            float2 sp = *(const float2*)(tb + 16);   // -sin m0,m1
            const float* up = uplane + y2 * 68 + i8;
            float4 uq0 = *(const float4*)(up);
            float4 uq1 = *(const float4*)(up + 4);
            fma4(A0r, cp.x, uq0);  fma4(A0i, sp.x, uq0);
            fma4(B0r, cp.x, uq1);  fma4(B0i, sp.x, uq1);
            fma4(A1r, cp.y, uq0);  fma4(A1i, sp.y, uq0);
            fma4(B1r, cp.y, uq1);  fma4(B1i, sp.y, uq1);
        }
    }

    // ky = 2m + p, m = 2kyq + d  ->  ky = 4kyq + 2d + p
    {
        int ky = 4 * kyq + p;
        float2* vp = V + (size_t)(b * HH + x) * 2048 + ky * 64 + i8;
        *(float4*)(vp)     = make_float4(A0r.x, A0i.x, A0r.y, A0i.y);
        *(float4*)(vp + 2) = make_float4(A0r.z, A0i.z, A0r.w, A0i.w);
        *(float4*)(vp + 4) = make_float4(B0r.x, B0i.x, B0r.y, B0i.y);
        *(float4*)(vp + 6) = make_float4(B0r.z, B0i.z, B0r.w, B0i.w);
    }
    {
        int ky = 4 * kyq + 2 + p;
        float2* vp = V + (size_t)(b * HH + x) * 2048 + ky * 64 + i8;
        *(float4*)(vp)     = make_float4(A1r.x, A1i.x, A1r.y, A1i.y);
        *(float4*)(vp + 2) = make_float4(A1r.z, A1i.z, A1r.w, A1i.w);
        *(float4*)(vp + 4) = make_float4(B1r.x, B1i.x, B1r.y, B1i.y);
        *(float4*)(vp + 6) = make_float4(B1r.z, B1i.z, B1r.w, B1i.w);
    }
}

// ---------------------------------------------------------------------------
// K2 (radix-2 GEMM): U[j][ky][b][i] = sum_{x<128} Tf[x][j] *
//                    (V[b][x][ky][i] + (-1)^j V[b][x+128][ky][i])
// grid = 1024: bx = jq + 4*(ky + 32*b). 256 threads.
// ---------------------------------------------------------------------------
__global__ __launch_bounds__(256) void k_fwd_x(const float2* __restrict__ Tf,
                                               const float2* __restrict__ V,
                                               float2* __restrict__ U) {
    __shared__ float sRe[2 * 2048];   // [par][xx*64+i] 16 KB
    __shared__ float sIm[2 * 2048];   // 16 KB
    __shared__ float2 Ts[32 * 16];    // [xx][jj] 4 KB

    int bx = blockIdx.x;
    int jq = bx & 3;
    int ky = (bx >> 2) & 31;
    int b  = bx >> 7;
    int t = threadIdx.x;
    int jr = t >> 5;      // 0..7
    int ir = t & 31;      // 0..31

    float2 a00 = {0,0}, a01 = {0,0}, a10 = {0,0}, a11 = {0,0};

    const float2* vb = V + (size_t)b * (HH * 2048) + ky * 64;
    int vrow = t >> 3;          // 0..31
    int vcol = (t & 7) * 8;     // complex index
    int tjj = (t & 7) * 2;      // 0..14
    int parOff = (jr & 1) * 2048;

    for (int x0 = 0; x0 < 128; x0 += 32) {
        const float2* plo = vb + (size_t)(x0 + vrow) * 2048 + vcol;
        const float2* phi = plo + 128 * 2048;
        float4 l0 = *(const float4*)(plo);
        float4 l1 = *(const float4*)(plo + 2);
        float4 l2 = *(const float4*)(plo + 4);
        float4 l3 = *(const float4*)(plo + 6);
        float4 h0 = *(const float4*)(phi);
        float4 h1 = *(const float4*)(phi + 2);
        float4 h2 = *(const float4*)(phi + 4);
        float4 h3 = *(const float4*)(phi + 6);
        float4 tv = *(const float4*)(Tf + (size_t)(x0 + vrow) * 64 + jq * 16 + tjj);

        __syncthreads();   // previous tile's LDS reads complete
        *(float4*)&Ts[vrow * 16 + tjj] = tv;
        int wb = vrow * 64 + vcol;
        *(float4*)(sRe + wb)            = make_float4(l0.x+h0.x, l0.z+h0.z, l1.x+h1.x, l1.z+h1.z);
        *(float4*)(sRe + wb + 4)        = make_float4(l2.x+h2.x, l2.z+h2.z, l3.x+h3.x, l3.z+h3.z);
        *(float4*)(sIm + wb)            = make_float4(l0.y+h0.y, l0.w+h0.w, l1.y+h1.y, l1.w+h1.w);
        *(float4*)(sIm + wb + 4)        = make_float4(l2.y+h2.y, l2.w+h2.w, l3.y+h3.y, l3.w+h3.w);
        *(float4*)(sRe + 2048 + wb)     = make_float4(l0.x-h0.x, l0.z-h0.z, l1.x-h1.x, l1.z-h1.z);
        *(float4*)(sRe + 2048 + wb + 4) = make_float4(l2.x-h2.x, l2.z-h2.z, l3.x-h3.x, l3.z-h3.z);
        *(float4*)(sIm + 2048 + wb)     = make_float4(l0.y-h0.y, l0.w-h0.w, l1.y-h1.y, l1.w-h1.w);
        *(float4*)(sIm + 2048 + wb + 4) = make_float4(l2.y-h2.y, l2.w-h2.w, l3.y-h3.y, l3.w-h3.w);
        __syncthreads();

        #pragma unroll
        for (int xx = 0; xx < 32; ++xx) {
            float2 t0 = Ts[xx * 16 + jr];
            float2 t1 = Ts[xx * 16 + jr + 8];
            const float* re = sRe + parOff + xx * 64;
            const float* im = sIm + parOff + xx * 64;
            float vr0 = re[ir], vr1 = re[ir + 32];
            float vi0 = im[ir], vi1 = im[ir + 32];
            a00.x += t0.x*vr0 - t0.y*vi0;  a00.y += t0.x*vi0 + t0.y*vr0;
            a01.x += t0.x*vr1 - t0.y*vi1;  a01.y += t0.x*vi1 + t0.y*vr1;
            a10.x += t1.x*vr0 - t1.y*vi0;  a10.y += t1.x*vi0 + t1.y*vr0;
            a11.x += t1.x*vr1 - t1.y*vi1;  a11.y += t1.x*vi1 + t1.y*vr1;
        }
    }

    int j0 = jq * 16 + jr;
    float2* u0 = U + ((size_t)(j0 * 32 + ky) * 8 + b) * 64 + ir;
    u0[0]  = a00;
    u0[32] = a01;
    float2* u1 = U + ((size_t)((j0 + 8) * 32 + ky) * 8 + b) * 64 + ir;
    u1[0]  = a10;
    u1[32] = a11;
}

// ---------------------------------------------------------------------------
// K3 (fused weight-transpose + mode mul, full-ky blocks):
// OF[b][ky][j][o] = sum_i U[j][ky][b][i] * (wr[i,o,kxl,ky], wi[i,o,kxl,ky])
// grid = 512: bx = j + 64*ot (ot 0..7 -> 8 o's). 256 threads.
// thread: og = t&7, bh = (t>>3)&7, kk = t>>6 (8 ky each). acc = 8 complex.
// Weight loads: 4 lanes x 32 B cover the FULL 128 B ky-run -> zero overfetch.
// LDS planar pitch-36 rows [i][b]/[i][o]: all compute b128 reads conflict-free.
// ---------------------------------------------------------------------------
__global__ __launch_bounds__(256, 2) void k_modew(const float* __restrict__ wpr,
                                                  const float* __restrict__ wpi,
                                                  const float* __restrict__ wnr,
                                                  const float* __restrict__ wni,
                                                  const float2* __restrict__ U,
                                                  float2* __restrict__ OF) {
    __shared__ float uRe[64 * 36];   // [(i*8+b)][ky]  9.2 KB
    __shared__ float uIm[64 * 36];
    __shared__ float wRe[64 * 36];   // [(i*8+og)][ky] 9.2 KB
    __shared__ float wIm[64 * 36];

    int bx = blockIdx.x;
    int j  = bx & 63;
    int ot = bx >> 6;          // 0..7
    int sel = j >> 5, kxl = j & 31;
    const float* sr = sel ? wnr : wpr;
    const float* si = sel ? wni : wpi;
    int t = threadIdx.x;
    int og = t & 7;
    int bh = (t >> 3) & 7;
    int kk = t >> 6;           // 0..3 -> ky = kk*8 + k
    // staging ids
    int sky = t >> 3;          // 0..31 (U stage: ky)
    int sb  = t & 7;           //        (U stage: b)
    int wig = t >> 5;          // 0..7  (W stage: i in tile)
    int wog = (t >> 2) & 7;    //        (W stage: o in tile)
    int wc  = t & 3;           //        (W stage: 8-ky chunk)

    float2 acc0 = {0,0}, acc1 = {0,0}, acc2 = {0,0}, acc3 = {0,0};
    float2 acc4 = {0,0}, acc5 = {0,0}, acc6 = {0,0}, acc7 = {0,0};

    for (int it = 0; it < 8; ++it) {
        // global loads (issue before barrier)
        const float2* up = U + ((size_t)(j * 32 + sky) * 8 + sb) * 64 + it * 8;
        float4 a0 = *(const float4*)(up);
        float4 a1 = *(const float4*)(up + 2);
        float4 a2 = *(const float4*)(up + 4);
        float4 a3 = *(const float4*)(up + 6);
        size_t wbase = (((size_t)((it * 8 + wig) * 64 + ot * 8 + wog)) * 32 + kxl) * 32 + wc * 8;
        float4 r0 = *(const float4*)(sr + wbase);
        float4 r1 = *(const float4*)(sr + wbase + 4);
        float4 q0 = *(const float4*)(si + wbase);
        float4 q1 = *(const float4*)(si + wbase + 4);

        __syncthreads();   // previous tile's LDS reads complete
        {
            // uS: [(i*8+b)][ky], thread (sky, sb) writes i=0..7
            float* urp = uRe + sb * 36 + sky;
            float* uip = uIm + sb * 36 + sky;
            urp[0*288] = a0.x;  uip[0*288] = a0.y;
            urp[1*288] = a0.z;  uip[1*288] = a0.w;
            urp[2*288] = a1.x;  uip[2*288] = a1.y;
            urp[3*288] = a1.z;  uip[3*288] = a1.w;
            urp[4*288] = a2.x;  uip[4*288] = a2.y;
            urp[5*288] = a2.z;  uip[5*288] = a2.w;
            urp[6*288] = a3.x;  uip[6*288] = a3.y;
            urp[7*288] = a3.z;  uip[7*288] = a3.w;
            // wS: [(i*8+og)][ky], thread (wig, wog, wc) writes 8 ky
            float* wrp = wRe + (wig * 8 + wog) * 36 + wc * 8;
            float* wip = wIm + (wig * 8 + wog) * 36 + wc * 8;
            wrp[0] = r0.x; wrp[1] = r0.y; wrp[2] = r0.z; wrp[3] = r0.w;
            wrp[4] = r1.x; wrp[5] = r1.y; wrp[6] = r1.z; wrp[7] = r1.w;
            wip[0] = q0.x; wip[1] = q0.y; wip[2] = q0.z; wip[3] = q0.w;
            wip[4] = q1.x; wip[5] = q1.y; wip[6] = q1.z; wip[7] = q1.w;
        }
        __syncthreads();

        #pragma unroll
        for (int i = 0; i < 8; ++i) {
            const float* urp = uRe + (i * 8 + bh) * 36 + kk * 8;
            float4 ur0 = *(const float4*)(urp);
            float4 ur1 = *(const float4*)(urp + 4);
            const float* uip = uIm + (i * 8 + bh) * 36 + kk * 8;
            float4 ui0 = *(const float4*)(uip);
            float4 ui1 = *(const float4*)(uip + 4);
            const float* wrp = wRe + (i * 8 + og) * 36 + kk * 8;
            float4 wr0 = *(const float4*)(wrp);
            float4 wr1 = *(const float4*)(wrp + 4);
            const float* wip = wIm + (i * 8 + og) * 36 + kk * 8;
            float4 wi0 = *(const float4*)(wip);
            float4 wi1 = *(const float4*)(wip + 4);
            acc0.x += ur0.x*wr0.x - ui0.x*wi0.x;  acc0.y += ur0.x*wi0.x + ui0.x*wr0.x;
            acc1.x += ur0.y*wr0.y - ui0.y*wi0.y;  acc1.y += ur0.y*wi0.y + ui0.y*wr0.y;
            acc2.x += ur0.z*wr0.z - ui0.z*wi0.z;  acc2.y += ur0.z*wi0.z + ui0.z*wr0.z;
            acc3.x += ur0.w*wr0.w - ui0.w*wi0.w;  acc3.y += ur0.w*wi0.w + ui0.w*wr0.w;
            acc4.x += ur1.x*wr1.x - ui1.x*wi1.x;  acc4.y += ur1.x*wi1.x + ui1.x*wr1.x;
            acc5.x += ur1.y*wr1.y - ui1.y*wi1.y;  acc5.y += ur1.y*wi1.y + ui1.y*wr1.y;
            acc6.x += ur1.z*wr1.z - ui1.z*wi1.z;  acc6.y += ur1.z*wi1.z + ui1.z*wr1.z;
            acc7.x += ur1.w*wr1.w - ui1.w*wi1.w;  acc7.y += ur1.w*wi1.w + ui1.w*wr1.w;
        }
    }

    int ogg = ot * 8 + og;
    int ky0 = kk * 8;
    OF[((size_t)(bh * 32 + ky0 + 0) * 64 + j) * 64 + ogg] = acc0;
    OF[((size_t)(bh * 32 + ky0 + 1) * 64 + j) * 64 + ogg] = acc1;
    OF[((size_t)(bh * 32 + ky0 + 2) * 64 + j) * 64 + ogg] = acc2;
    OF[((size_t)(bh * 32 + ky0 + 3) * 64 + j) * 64 + ogg] = acc3;
    OF[((size_t)(bh * 32 + ky0 + 4) * 64 + j) * 64 + ogg] = acc4;
    OF[((size_t)(bh * 32 + ky0 + 5) * 64 + j) * 64 + ogg] = acc5;
    OF[((size_t)(bh * 32 + ky0 + 6) * 64 + j) * 64 + ogg] = acc6;
    OF[((size_t)(bh * 32 + ky0 + 7) * 64 + j) * 64 + ogg] = acc7;
}

// ---------------------------------------------------------------------------
// K4 (radix-2 GEMM): for x<128:
//   Se = sum_{even j} Ti[j][x] OF[b][ky][j][o], So = sum_{odd j} ...
//   A[b][x]     = (Se+So)*sc,  A[b][x+128] = (Se-So)*sc   (sc: ky==0 -> 0.5)
// grid = 1024: bx = xt + 4*(ky + 32*b). 256 threads.
// ---------------------------------------------------------------------------
__global__ __launch_bounds__(256) void k_inv_x(const float2* __restrict__ Ti,
                                               const float2* __restrict__ OF,
                                               float2* __restrict__ A) {
    __shared__ float2 Ts[32 * 32];   // [jj][xp]  8 KB
    __shared__ float2 Os[32 * 64];   // [jj][o]  16 KB

    int bx = blockIdx.x;
    int xt = bx & 3;
    int ky = (bx >> 2) & 31;
    int b  = bx >> 7;
    int t = threadIdx.x;
    int or_ = t & 15;
    int xr = t >> 4;     // 0..15

    float2 acc[2][2][4];   // [parity][p][q]
    #pragma unroll
    for (int pa = 0; pa < 2; ++pa)
        #pragma unroll
        for (int p = 0; p < 2; ++p)
            #pragma unroll
            for (int q = 0; q < 4; ++q) acc[pa][p][q] = make_float2(0.f, 0.f);

    const float2* ofb = OF + (size_t)(b * 32 + ky) * 4096;
    int sj = t >> 3;         // 0..31
    int sx = (t & 7) * 4;    // Ts cols (4 complex)
    int so = (t & 7) * 8;    // Os cols (8 complex)

    for (int kh = 0; kh < 2; ++kh) {
        const float2* tsrc = Ti + (size_t)(kh * 32 + sj) * 256 + xt * 32 + sx;
        float4 t0 = *(const float4*)(tsrc);
        float4 t1 = *(const float4*)(tsrc + 2);
        const float2* osrc = ofb + (size_t)(kh * 32 + sj) * 64 + so;
        float4 o0 = *(const float4*)(osrc);
        float4 o1 = *(const float4*)(osrc + 2);
        float4 o2 = *(const float4*)(osrc + 4);
        float4 o3 = *(const float4*)(osrc + 6);

        __syncthreads();
        *(float4*)&Ts[sj * 32 + sx]     = t0;
        *(float4*)&Ts[sj * 32 + sx + 2] = t1;
        float2* od = &Os[sj * 64 + so];
        *(float4*)(od)     = o0;
        *(float4*)(od + 2) = o1;
        *(float4*)(od + 4) = o2;
        *(float4*)(od + 6) = o3;
        __syncthreads();

        #pragma unroll
        for (int jj = 0; jj < 32; ++jj) {
            float4 tp = *(const float4*)&Ts[jj * 32 + xr * 2];
            float2 q0 = Os[jj * 64 + or_];
            float2 q1 = Os[jj * 64 + or_ + 16];
            float2 q2 = Os[jj * 64 + or_ + 32];
            float2 q3 = Os[jj * 64 + or_ + 48];
            const int pa = jj & 1;     // constant after unroll
            cmac(acc[pa][0][0], tp.x, tp.y, q0);
            cmac(acc[pa][0][1], tp.x, tp.y, q1);
            cmac(acc[pa][0][2], tp.x, tp.y, q2);
            cmac(acc[pa][0][3], tp.x, tp.y, q3);
            cmac(acc[pa][1][0], tp.z, tp.w, q0);
            cmac(acc[pa][1][1], tp.z, tp.w, q1);
            cmac(acc[pa][1][2], tp.z, tp.w, q2);
            cmac(acc[pa][1][3], tp.z, tp.w, q3);
        }
    }

    float sc = (ky == 0) ? 0.5f : 1.0f;
    #pragma unroll
    for (int p = 0; p < 2; ++p) {
        int x = xt * 32 + xr * 2 + p;
        float2* alo = A + ((size_t)(b * 256 + x) * 32 + ky) * 64 + or_;
        float2* ahi = A + ((size_t)(b * 256 + x + 128) * 32 + ky) * 64 + or_;
        #pragma unroll
        for (int q = 0; q < 4; ++q) {
            float2 se = acc[0][p][q], so2 = acc[1][p][q];
            alo[16 * q] = make_float2((se.x + so2.x) * sc, (se.y + so2.y) * sc);
            ahi[16 * q] = make_float2((se.x - so2.x) * sc, (se.y - so2.y) * sc);
        }
    }
}

// ---------------------------------------------------------------------------
// K5 (GEMM form): per (b,x):
//   S_pi[p][o] = sum_j T2[pi][j][p] * A'[pi][j][o]   (j = 16m x {re,im}, K=32)
//   out[p][o] = S_0+S_1 ; out[p+128][o] = S_0-S_1    (p in [0,128))
// grid = B*H blocks, 512 threads: o4 = (t&15)*4, pr = t>>4 (p = pr*4+pp).
// ---------------------------------------------------------------------------
__global__ __launch_bounds__(512, 2) void k_inv_y(const float* __restrict__ T2g,
                                                  const float2* __restrict__ A,
                                                  float* __restrict__ out) {
    __shared__ float As[2 * 32 * 68];     // [pi][j][o]+pad   17.4 KB
    __shared__ float T2s[2 * 32 * 132];   // [pi][j][p]+pad   33.8 KB

    int t = threadIdx.x;
    int b = blockIdx.x >> 8;
    int x = blockIdx.x & 255;
    int o4 = (t & 15) * 4;
    int pr = t >> 4;            // 0..31 -> p = pr*4 + pp

    float acc[2][4][4];
    #pragma unroll
    for (int pi = 0; pi < 2; ++pi)
        #pragma unroll
        for (int pp = 0; pp < 4; ++pp)
            #pragma unroll
            for (int k = 0; k < 4; ++k) acc[pi][pp][k] = 0.f;

    // stage A' planar: A[b][x][ky][o] -> As[ky&1][2*(ky>>1)+{re,im}][o]
    {
        int ky = t >> 4;            // 0..31
        int oc = (t & 15) * 4;      // complex col
        const float2* ap = A + (size_t)(b * 256 + x) * 2048 + ky * 64 + oc;
        float4 g0 = *(const float4*)(ap);
        float4 g1 = *(const float4*)(ap + 2);
        int pi = ky & 1, m = ky >> 1;
        float* re = As + ((pi * 32) + 2 * m) * 68 + oc;
        float* im = As + ((pi * 32) + 2 * m + 1) * 68 + oc;
        *(float4*)(re) = make_float4(g0.x, g0.z, g1.x, g1.z);
        *(float4*)(im) = make_float4(g0.y, g0.w, g1.y, g1.w);
    }
    // stage full T2: 8192 floats / 512 threads = 16 floats = 4 float4
    {
        int row = t >> 3;           // 0..63 = pi*32 + j
        int c = (t & 7) * 16;       // 0..112
        const float* tg = T2g + (size_t)row * 128 + c;
        float4 q0 = *(const float4*)(tg);
        float4 q1 = *(const float4*)(tg + 4);
        float4 q2 = *(const float4*)(tg + 8);
        float4 q3 = *(const float4*)(tg + 12);
        float* td = T2s + row * 132 + c;
        *(float4*)(td)      = q0;
        *(float4*)(td + 4)  = q1;
        *(float4*)(td + 8)  = q2;
        *(float4*)(td + 12) = q3;
    }
    __syncthreads();

    #pragma unroll
    for (int pi = 0; pi < 2; ++pi) {
        #pragma unroll
        for (int jj = 0; jj < 32; ++jj) {
            float4 ta = *(const float4*)(T2s + (pi * 32 + jj) * 132 + pr * 4);
            float4 av = *(const float4*)(As + (pi * 32 + jj) * 68 + o4);
            acc[pi][0][0] += ta.x * av.x;  acc[pi][0][1] += ta.x * av.y;
            acc[pi][0][2] += ta.x * av.z;  acc[pi][0][3] += ta.x * av.w;
            acc[pi][1][0] += ta.y * av.x;  acc[pi][1][1] += ta.y * av.y;
            acc[pi][1][2] += ta.y * av.z;  acc[pi][1][3] += ta.y * av.w;
            acc[pi][2][0] += ta.z * av.x;  acc[pi][2][1] += ta.z * av.y;
            acc[pi][2][2] += ta.z * av.z;  acc[pi][2][3] += ta.z * av.w;
            acc[pi][3][0] += ta.w * av.x;  acc[pi][3][1] += ta.w * av.y;
            acc[pi][3][2] += ta.w * av.z;  acc[pi][3][3] += ta.w * av.w;
        }
    }

    float* op = out + (size_t)(b * 256 + x) * (256 * 64);
    #pragma unroll
    for (int pp = 0; pp < 4; ++pp) {
        int p = pr * 4 + pp;
        float4 lo = make_float4(acc[0][pp][0] + acc[1][pp][0],
                                acc[0][pp][1] + acc[1][pp][1],
                                acc[0][pp][2] + acc[1][pp][2],
                                acc[0][pp][3] + acc[1][pp][3]);
        float4 hi = make_float4(acc[0][pp][0] - acc[1][pp][0],
                                acc[0][pp][1] - acc[1][pp][1],
                                acc[0][pp][2] - acc[1][pp][2],
                                acc[0][pp][3] - acc[1][pp][3]);
        *(float4*)(op + (size_t)p * 64 + o4)         = lo;
        *(float4*)(op + (size_t)(p + 128) * 64 + o4) = hi;
    }
}

// ---------------------------------------------------------------------------
extern "C" void kernel_launch(void* const* d_in, const int* in_sizes, int n_in,
                              void* d_out, int out_size, void* d_ws, size_t ws_size,
                              hipStream_t stream) {
    const float* u   = (const float*)d_in[0];
    const float* wpr = (const float*)d_in[1];
    const float* wpi = (const float*)d_in[2];
    const float* wnr = (const float*)d_in[3];
    const float* wni = (const float*)d_in[4];
    float* out = (float*)d_out;

    char* ws = (char*)d_ws;
    // U : 64*32*8*64  float2 =  8 MiB  @ 0
    // OF:  8*32*64*64 float2 =  8 MiB  @ 8 MiB
    // V : 8*256*32*64 float2 = 32 MiB  @ 16 MiB (A aliases V)
    // Tf: 128 KiB @ 48 MiB; Ti: 128 KiB; Ty: 32 KiB; T2: 32 KiB
    float2* U  = (float2*)(ws);
    float2* OF = (float2*)(ws + 8388608);
    float2* V  = (float2*)(ws + 16777216);
    float2* A  = V;
    float2* Tf = (float2*)(ws + 50331648);
    float2* Ti = (float2*)(ws + 50331648 + 131072);
    float*  Ty = (float*)(ws + 50331648 + 262144);
    float*  T2 = (float*)(ws + 50331648 + 262144 + 32768);

    k_tw<<<128, 256, 0, stream>>>(Tf, Ti, Ty, T2);
    k_fwd_y<<<BB * HH, 128, 0, stream>>>(u, Ty, V);
    k_fwd_x<<<1024, 256, 0, stream>>>(Tf, V, U);
    k_modew<<<512, 256, 0, stream>>>(wpr, wpi, wnr, wni, U, OF);
    k_inv_x<<<1024, 256, 0, stream>>>(Ti, OF, A);
    k_inv_y<<<BB * HH, 512, 0, stream>>>(T2, A, out);
}

// Round 8
// 233.120 us; speedup vs baseline: 1.1671x; 1.1671x over previous
//
#include <hip/hip_runtime.h>
#include <math.h>

// Sizes fixed by the problem.
#define BB 8
#define HH 256
#define WW 256
#define CC 64
// modes: kx in {0..31} u {224..255} (64 total), ky in {0..31}

__device__ inline void cmac(float2& a, float tx, float ty, float2 v) {
    a.x += tx * v.x - ty * v.y;
    a.y += tx * v.y + ty * v.x;
}
__device__ inline void fma4(float4& a, float s, float4 v) {
    a.x += s * v.x; a.y += s * v.y; a.z += s * v.z; a.w += s * v.w;
}

// ---------------------------------------------------------------------------
// K0: all twiddle tables (one kernel, 128 blocks x 256).
// Tf[x][j]  = e^{-2pi i kxa(j) x/256}                       (fwd x-DFT)
// Ti[j][x]  = (2/65536) e^{+2pi i kxa(j) x/256}             (inv x-DFT)
// Ty[y'][par*32+cs*16+m]: cs=0 -> cos(2pi ky y'/256), cs=1 -> -sin(...),
//                         ky = 2m+par                        (fwd y-DFT)
// T2[(pi*32+j)*128+p]: j=2m+ri; ri=0 -> cos(2pi ky p/256), ri=1 -> -sin(...),
//                         ky = 2m+pi                         (inv y-DFT)
// kxa(j) = j (j<32) else j+192.  parity(kxa(j)) == parity(j).
// ---------------------------------------------------------------------------
__global__ __launch_bounds__(256) void k_tw(float2* __restrict__ Tf,
                                            float2* __restrict__ Ti,
                                            float* __restrict__ Ty,
                                            float* __restrict__ T2) {
    int e = blockIdx.x * 256 + threadIdx.x;   // 0..32767
    if (e < 16384) {
        int x = e >> 6;
        int j = e & 63;
        int kxa = j + ((j >> 5) * 192);
        int tt = (kxa * x) & 255;
        float ang = (float)tt * (6.283185307179586f / 256.0f);
        float s, c;
        sincosf(ang, &s, &c);
        Tf[(size_t)x * 64 + j] = make_float2(c, -s);
        const float k = 2.0f / 65536.0f;
        Ti[(size_t)j * 256 + x] = make_float2(c * k, s * k);
    } else {
        int f = e - 16384;
        if (f < 8192) {
            int yp = f >> 6;
            int col = f & 63;
            int par = (col >> 5) & 1;
            int cs = (col >> 4) & 1;
            int m = col & 15;
            int ky = 2 * m + par;
            int tt = (ky * yp) & 255;
            float ang = (float)tt * (6.283185307179586f / 256.0f);
            float s, c;
            sincosf(ang, &s, &c);
            Ty[f] = cs ? -s : c;
        } else {
            int g = f - 8192;
            int pi = g >> 12;
            int j = (g >> 7) & 31;
            int p = g & 127;
            int m = j >> 1, ri = j & 1;
            int ky = 2 * m + pi;
            int tt = (ky * p) & 255;
            float ang = (float)tt * (6.283185307179586f / 256.0f);
            float s, c;
            sincosf(ang, &s, &c);
            T2[g] = ri ? -s : c;
        }
    }
}

// ---------------------------------------------------------------------------
// K1 (GEMM form, R_i=8): V[b][x][ky][i] = sum_{y'<128} Ty[y'][ky-col] *
//                 (u[y'] + (-1)^ky u[y'+128])[i]
// grid = B*H (one (b,x) row), 128 threads (2 waves).
// ---------------------------------------------------------------------------
__global__ __launch_bounds__(128, 3) void k_fwd_y(const float* __restrict__ u,
                                                  const float* __restrict__ Ty,
                                                  float2* __restrict__ V) {
    __shared__ float ue[32 * 68];
    __shared__ float uo[32 * 68];
    __shared__ float Tt[32 * 68];

    int t = threadIdx.x;
    int b = blockIdx.x >> 8;
    int x = blockIdx.x & 255;
    int i8 = (t & 7) * 8;
    int w = t >> 3;      // 0..15
    int p = w & 1;
    int kyq = w >> 1;    // 0..7
    int yy = t >> 2;     // 0..31
    int c0 = (t & 3) * 16;

    const float* ub = u + ((size_t)(b * HH + x)) * (WW * CC);
    const float* uplane = p ? uo : ue;

    float4 A0r = {0,0,0,0}, A0i = {0,0,0,0};   // m0, i8+0..3
    float4 B0r = {0,0,0,0}, B0i = {0,0,0,0};   // m0, i8+4..7
    float4 A1r = {0,0,0,0}, A1i = {0,0,0,0};   // m1, i8+0..3
    float4 B1r = {0,0,0,0}, B1i = {0,0,0,0};   // m1, i8+4..7

    for (int yt = 0; yt < 4; ++yt) {
        const float* plo = ub + (size_t)(yt * 32 + yy) * CC + c0;
        const float* phi = plo + 128 * CC;
        float4 l0 = *(const float4*)(plo);
        float4 l1 = *(const float4*)(plo + 4);
        float4 l2 = *(const float4*)(plo + 8);
        float4 l3 = *(const float4*)(plo + 12);
        float4 h0 = *(const float4*)(phi);
        float4 h1 = *(const float4*)(phi + 4);
        float4 h2 = *(const float4*)(phi + 8);
        float4 h3 = *(const float4*)(phi + 12);
        const float* tsrc = Ty + (size_t)(yt * 32 + yy) * 64 + c0;
        float4 t0 = *(const float4*)(tsrc);
        float4 t1 = *(const float4*)(tsrc + 4);
        float4 t2 = *(const float4*)(tsrc + 8);
        float4 t3 = *(const float4*)(tsrc + 12);

        __syncthreads();   // previous tile's LDS reads complete
        int wb = yy * 68 + c0;
        *(float4*)(ue + wb)      = make_float4(l0.x+h0.x, l0.y+h0.y, l0.z+h0.z, l0.w+h0.w);
        *(float4*)(ue + wb + 4)  = make_float4(l1.x+h1.x, l1.y+h1.y, l1.z+h1.z, l1.w+h1.w);
        *(float4*)(ue + wb + 8)  = make_float4(l2.x+h2.x, l2.y+h2.y, l2.z+h2.z, l2.w+h2.w);
        *(float4*)(ue + wb + 12) = make_float4(l3.x+h3.x, l3.y+h3.y, l3.z+h3.z, l3.w+h3.w);
        *(float4*)(uo + wb)      = make_float4(l0.x-h0.x, l0.y-h0.y, l0.z-h0.z, l0.w-h0.w);
        *(float4*)(uo + wb + 4)  = make_float4(l1.x-h1.x, l1.y-h1.y, l1.z-h1.z, l1.w-h1.w);
        *(float4*)(uo + wb + 8)  = make_float4(l2.x-h2.x, l2.y-h2.y, l2.z-h2.z, l2.w-h2.w);
        *(float4*)(uo + wb + 12) = make_float4(l3.x-h3.x, l3.y-h3.y, l3.z-h3.z, l3.w-h3.w);
        *(float4*)(Tt + wb)      = t0;
        *(float4*)(Tt + wb + 4)  = t1;
        *(float4*)(Tt + wb + 8)  = t2;
        *(float4*)(Tt + wb + 12) = t3;
        __syncthreads();

        #pragma unroll
        for (int y2 = 0; y2 < 32; ++y2) {
            const float* tb = Tt + y2 * 68 + p * 32 + kyq * 2;
            float2 cp = *(const float2*)(tb);        // cos  m0,m1
            float2 sp = *(const float2*)(tb + 16);   // -sin m0,m1
            const float* up = uplane + y2 * 68 + i8;
            float4 uq0 = *(const float4*)(up);
            float4 uq1 = *(const float4*)(up + 4);
            fma4(A0r, cp.x, uq0);  fma4(A0i, sp.x, uq0);
            fma4(B0r, cp.x, uq1);  fma4(B0i, sp.x, uq1);
            fma4(A1r, cp.y, uq0);  fma4(A1i, sp.y, uq0);
            fma4(B1r, cp.y, uq1);  fma4(B1i, sp.y, uq1);
        }
    }

    // ky = 2m + p, m = 2kyq + d  ->  ky = 4kyq + 2d + p
    {
        int ky = 4 * kyq + p;
        float2* vp = V + (size_t)(b * HH + x) * 2048 + ky * 64 + i8;
        *(float4*)(vp)     = make_float4(A0r.x, A0i.x, A0r.y, A0i.y);
        *(float4*)(vp + 2) = make_float4(A0r.z, A0i.z, A0r.w, A0i.w);
        *(float4*)(vp + 4) = make_float4(B0r.x, B0i.x, B0r.y, B0i.y);
        *(float4*)(vp + 6) = make_float4(B0r.z, B0i.z, B0r.w, B0i.w);
    }
    {
        int ky = 4 * kyq + 2 + p;
        float2* vp = V + (size_t)(b * HH + x) * 2048 + ky * 64 + i8;
        *(float4*)(vp)     = make_float4(A1r.x, A1i.x, A1r.y, A1i.y);
        *(float4*)(vp + 2) = make_float4(A1r.z, A1i.z, A1r.w, A1i.w);
        *(float4*)(vp + 4) = make_float4(B1r.x, B1i.x, B1r.y, B1i.y);
        *(float4*)(vp + 6) = make_float4(B1r.z, B1i.z, B1r.w, B1i.w);
    }
}

// ---------------------------------------------------------------------------
// K2 (radix-2 GEMM): U[j][ky][b][i] = sum_{x<128} Tf[x][j] *
//                    (V[b][x][ky][i] + (-1)^j V[b][x+128][ky][i])
// grid = 1024: bx = jq + 4*(ky + 32*b). 256 threads.
// ---------------------------------------------------------------------------
__global__ __launch_bounds__(256) void k_fwd_x(const float2* __restrict__ Tf,
                                               const float2* __restrict__ V,
                                               float2* __restrict__ U) {
    __shared__ float sRe[2 * 2048];   // [par][xx*64+i] 16 KB
    __shared__ float sIm[2 * 2048];   // 16 KB
    __shared__ float2 Ts[32 * 16];    // [xx][jj] 4 KB

    int bx = blockIdx.x;
    int jq = bx & 3;
    int ky = (bx >> 2) & 31;
    int b  = bx >> 7;
    int t = threadIdx.x;
    int jr = t >> 5;      // 0..7
    int ir = t & 31;      // 0..31

    float2 a00 = {0,0}, a01 = {0,0}, a10 = {0,0}, a11 = {0,0};

    const float2* vb = V + (size_t)b * (HH * 2048) + ky * 64;
    int vrow = t >> 3;          // 0..31
    int vcol = (t & 7) * 8;     // complex index
    int tjj = (t & 7) * 2;      // 0..14
    int parOff = (jr & 1) * 2048;

    for (int x0 = 0; x0 < 128; x0 += 32) {
        const float2* plo = vb + (size_t)(x0 + vrow) * 2048 + vcol;
        const float2* phi = plo + 128 * 2048;
        float4 l0 = *(const float4*)(plo);
        float4 l1 = *(const float4*)(plo + 2);
        float4 l2 = *(const float4*)(plo + 4);
        float4 l3 = *(const float4*)(plo + 6);
        float4 h0 = *(const float4*)(phi);
        float4 h1 = *(const float4*)(phi + 2);
        float4 h2 = *(const float4*)(phi + 4);
        float4 h3 = *(const float4*)(phi + 6);
        float4 tv = *(const float4*)(Tf + (size_t)(x0 + vrow) * 64 + jq * 16 + tjj);

        __syncthreads();   // previous tile's LDS reads complete
        *(float4*)&Ts[vrow * 16 + tjj] = tv;
        int wb = vrow * 64 + vcol;
        *(float4*)(sRe + wb)            = make_float4(l0.x+h0.x, l0.z+h0.z, l1.x+h1.x, l1.z+h1.z);
        *(float4*)(sRe + wb + 4)        = make_float4(l2.x+h2.x, l2.z+h2.z, l3.x+h3.x, l3.z+h3.z);
        *(float4*)(sIm + wb)            = make_float4(l0.y+h0.y, l0.w+h0.w, l1.y+h1.y, l1.w+h1.w);
        *(float4*)(sIm + wb + 4)        = make_float4(l2.y+h2.y, l2.w+h2.w, l3.y+h3.y, l3.w+h3.w);
        *(float4*)(sRe + 2048 + wb)     = make_float4(l0.x-h0.x, l0.z-h0.z, l1.x-h1.x, l1.z-h1.z);
        *(float4*)(sRe + 2048 + wb + 4) = make_float4(l2.x-h2.x, l2.z-h2.z, l3.x-h3.x, l3.z-h3.z);
        *(float4*)(sIm + 2048 + wb)     = make_float4(l0.y-h0.y, l0.w-h0.w, l1.y-h1.y, l1.w-h1.w);
        *(float4*)(sIm + 2048 + wb + 4) = make_float4(l2.y-h2.y, l2.w-h2.w, l3.y-h3.y, l3.w-h3.w);
        __syncthreads();

        #pragma unroll
        for (int xx = 0; xx < 32; ++xx) {
            float2 t0 = Ts[xx * 16 + jr];
            float2 t1 = Ts[xx * 16 + jr + 8];
            const float* re = sRe + parOff + xx * 64;
            const float* im = sIm + parOff + xx * 64;
            float vr0 = re[ir], vr1 = re[ir + 32];
            float vi0 = im[ir], vi1 = im[ir + 32];
            a00.x += t0.x*vr0 - t0.y*vi0;  a00.y += t0.x*vi0 + t0.y*vr0;
            a01.x += t0.x*vr1 - t0.y*vi1;  a01.y += t0.x*vi1 + t0.y*vr1;
            a10.x += t1.x*vr0 - t1.y*vi0;  a10.y += t1.x*vi0 + t1.y*vr0;
            a11.x += t1.x*vr1 - t1.y*vi1;  a11.y += t1.x*vi1 + t1.y*vr1;
        }
    }

    int j0 = jq * 16 + jr;
    float2* u0 = U + ((size_t)(j0 * 32 + ky) * 8 + b) * 64 + ir;
    u0[0]  = a00;
    u0[32] = a01;
    float2* u1 = U + ((size_t)((j0 + 8) * 32 + ky) * 8 + b) * 64 + ir;
    u1[0]  = a10;
    u1[32] = a11;
}

// ---------------------------------------------------------------------------
// K3 (fused weight-transpose + mode mul, full-ky blocks, LDS double-buffer):
// OF[b][ky][j][o] = sum_i U[j][ky][b][i] * (wr[i,o,kxl,ky], wi[i,o,kxl,ky])
// grid = 512: bx = j + 64*ot (ot 0..7 -> 8 o's). 256 threads.
// Ping-pong buffers, ONE barrier/iter: stage(it+1)->buf[cur^1] runs during
// compute(buf[cur]); staged regs live only load->ds_write (no cross-barrier
// live range -> no spill). Weight reads cover full 128 B ky-runs (zero
// overfetch, proven FETCH=64.5 MB). LDS 72 KB -> 2 blocks/CU, grid resident.
// ---------------------------------------------------------------------------
__global__ __launch_bounds__(256) void k_modew(const float* __restrict__ wpr,
                                               const float* __restrict__ wpi,
                                               const float* __restrict__ wnr,
                                               const float* __restrict__ wni,
                                               const float2* __restrict__ U,
                                               float2* __restrict__ OF) {
    __shared__ float uRe[2][64 * 36];   // [(i*8+b)][ky]  9 KB each
    __shared__ float uIm[2][64 * 36];
    __shared__ float wRe[2][64 * 36];   // [(i*8+og)][ky] 9 KB each
    __shared__ float wIm[2][64 * 36];

    int bx = blockIdx.x;
    int j  = bx & 63;
    int ot = bx >> 6;          // 0..7
    int sel = j >> 5, kxl = j & 31;
    const float* sr = sel ? wnr : wpr;
    const float* si = sel ? wni : wpi;
    int t = threadIdx.x;
    int og = t & 7;
    int bh = (t >> 3) & 7;
    int kk = t >> 6;           // 0..3 -> ky = kk*8 + k
    // staging ids
    int sky = t >> 3;          // 0..31 (U stage: ky)
    int sb  = t & 7;           //        (U stage: b)
    int wig = t >> 5;          // 0..7  (W stage: i in tile)
    int wog = (t >> 2) & 7;    //        (W stage: o in tile)
    int wc  = t & 3;           //        (W stage: 8-ky chunk)

    float2 acc0 = {0,0}, acc1 = {0,0}, acc2 = {0,0}, acc3 = {0,0};
    float2 acc4 = {0,0}, acc5 = {0,0}, acc6 = {0,0}, acc7 = {0,0};

    auto stage = [&](int it, int buf) {
        const float2* up = U + ((size_t)(j * 32 + sky) * 8 + sb) * 64 + it * 8;
        float4 a0 = *(const float4*)(up);
        float4 a1 = *(const float4*)(up + 2);
        float4 a2 = *(const float4*)(up + 4);
        float4 a3 = *(const float4*)(up + 6);
        size_t wbase = (((size_t)((it * 8 + wig) * 64 + ot * 8 + wog)) * 32 + kxl) * 32 + wc * 8;
        float4 r0 = *(const float4*)(sr + wbase);
        float4 r1 = *(const float4*)(sr + wbase + 4);
        float4 q0 = *(const float4*)(si + wbase);
        float4 q1 = *(const float4*)(si + wbase + 4);
        // uS: [(i*8+b)][ky]
        float* urp = uRe[buf] + sb * 36 + sky;
        float* uip = uIm[buf] + sb * 36 + sky;
        urp[0*288] = a0.x;  uip[0*288] = a0.y;
        urp[1*288] = a0.z;  uip[1*288] = a0.w;
        urp[2*288] = a1.x;  uip[2*288] = a1.y;
        urp[3*288] = a1.z;  uip[3*288] = a1.w;
        urp[4*288] = a2.x;  uip[4*288] = a2.y;
        urp[5*288] = a2.z;  uip[5*288] = a2.w;
        urp[6*288] = a3.x;  uip[6*288] = a3.y;
        urp[7*288] = a3.z;  uip[7*288] = a3.w;
        // wS: [(i*8+og)][ky]  (rows 144 B-pitch, 16 B-aligned -> float4 ok)
        float* wrp = wRe[buf] + (wig * 8 + wog) * 36 + wc * 8;
        float* wip = wIm[buf] + (wig * 8 + wog) * 36 + wc * 8;
        *(float4*)(wrp)     = r0;
        *(float4*)(wrp + 4) = r1;
        *(float4*)(wip)     = q0;
        *(float4*)(wip + 4) = q1;
    };

    stage(0, 0);
    __syncthreads();

    for (int it = 0; it < 8; ++it) {
        int cur = it & 1;
        if (it < 7) stage(it + 1, cur ^ 1);   // overlaps with compute below

        #pragma unroll
        for (int i = 0; i < 8; ++i) {
            const float* urp = uRe[cur] + (i * 8 + bh) * 36 + kk * 8;
            float4 ur0 = *(const float4*)(urp);
            float4 ur1 = *(const float4*)(urp + 4);
            const float* uip = uIm[cur] + (i * 8 + bh) * 36 + kk * 8;
            float4 ui0 = *(const float4*)(uip);
            float4 ui1 = *(const float4*)(uip + 4);
            const float* wrp = wRe[cur] + (i * 8 + og) * 36 + kk * 8;
            float4 wr0 = *(const float4*)(wrp);
            float4 wr1 = *(const float4*)(wrp + 4);
            const float* wip = wIm[cur] + (i * 8 + og) * 36 + kk * 8;
            float4 wi0 = *(const float4*)(wip);
            float4 wi1 = *(const float4*)(wip + 4);
            acc0.x += ur0.x*wr0.x - ui0.x*wi0.x;  acc0.y += ur0.x*wi0.x + ui0.x*wr0.x;
            acc1.x += ur0.y*wr0.y - ui0.y*wi0.y;  acc1.y += ur0.y*wi0.y + ui0.y*wr0.y;
            acc2.x += ur0.z*wr0.z - ui0.z*wi0.z;  acc2.y += ur0.z*wi0.z + ui0.z*wr0.z;
            acc3.x += ur0.w*wr0.w - ui0.w*wi0.w;  acc3.y += ur0.w*wi0.w + ui0.w*wr0.w;
            acc4.x += ur1.x*wr1.x - ui1.x*wi1.x;  acc4.y += ur1.x*wi1.x + ui1.x*wr1.x;
            acc5.x += ur1.y*wr1.y - ui1.y*wi1.y;  acc5.y += ur1.y*wi1.y + ui1.y*wr1.y;
            acc6.x += ur1.z*wr1.z - ui1.z*wi1.z;  acc6.y += ur1.z*wi1.z + ui1.z*wr1.z;
            acc7.x += ur1.w*wr1.w - ui1.w*wi1.w;  acc7.y += ur1.w*wi1.w + ui1.w*wr1.w;
        }
        __syncthreads();   // buf[cur^1] writes visible; buf[cur] reads done
    }

    int ogg = ot * 8 + og;
    int ky0 = kk * 8;
    OF[((size_t)(bh * 32 + ky0 + 0) * 64 + j) * 64 + ogg] = acc0;
    OF[((size_t)(bh * 32 + ky0 + 1) * 64 + j) * 64 + ogg] = acc1;
    OF[((size_t)(bh * 32 + ky0 + 2) * 64 + j) * 64 + ogg] = acc2;
    OF[((size_t)(bh * 32 + ky0 + 3) * 64 + j) * 64 + ogg] = acc3;
    OF[((size_t)(bh * 32 + ky0 + 4) * 64 + j) * 64 + ogg] = acc4;
    OF[((size_t)(bh * 32 + ky0 + 5) * 64 + j) * 64 + ogg] = acc5;
    OF[((size_t)(bh * 32 + ky0 + 6) * 64 + j) * 64 + ogg] = acc6;
    OF[((size_t)(bh * 32 + ky0 + 7) * 64 + j) * 64 + ogg] = acc7;
}

// ---------------------------------------------------------------------------
// K4 (radix-2 GEMM): for x<128:
//   Se = sum_{even j} Ti[j][x] OF[b][ky][j][o], So = sum_{odd j} ...
//   A[b][x]     = (Se+So)*sc,  A[b][x+128] = (Se-So)*sc   (sc: ky==0 -> 0.5)
// grid = 1024: bx = xt + 4*(ky + 32*b). 256 threads.
// ---------------------------------------------------------------------------
__global__ __launch_bounds__(256) void k_inv_x(const float2* __restrict__ Ti,
                                               const float2* __restrict__ OF,
                                               float2* __restrict__ A) {
    __shared__ float2 Ts[32 * 32];   // [jj][xp]  8 KB
    __shared__ float2 Os[32 * 64];   // [jj][o]  16 KB

    int bx = blockIdx.x;
    int xt = bx & 3;
    int ky = (bx >> 2) & 31;
    int b  = bx >> 7;
    int t = threadIdx.x;
    int or_ = t & 15;
    int xr = t >> 4;     // 0..15

    float2 acc[2][2][4];   // [parity][p][q]
    #pragma unroll
    for (int pa = 0; pa < 2; ++pa)
        #pragma unroll
        for (int p = 0; p < 2; ++p)
            #pragma unroll
            for (int q = 0; q < 4; ++q) acc[pa][p][q] = make_float2(0.f, 0.f);

    const float2* ofb = OF + (size_t)(b * 32 + ky) * 4096;
    int sj = t >> 3;         // 0..31
    int sx = (t & 7) * 4;    // Ts cols (4 complex)
    int so = (t & 7) * 8;    // Os cols (8 complex)

    for (int kh = 0; kh < 2; ++kh) {
        const float2* tsrc = Ti + (size_t)(kh * 32 + sj) * 256 + xt * 32 + sx;
        float4 t0 = *(const float4*)(tsrc);
        float4 t1 = *(const float4*)(tsrc + 2);
        const float2* osrc = ofb + (size_t)(kh * 32 + sj) * 64 + so;
        float4 o0 = *(const float4*)(osrc);
        float4 o1 = *(const float4*)(osrc + 2);
        float4 o2 = *(const float4*)(osrc + 4);
        float4 o3 = *(const float4*)(osrc + 6);

        __syncthreads();
        *(float4*)&Ts[sj * 32 + sx]     = t0;
        *(float4*)&Ts[sj * 32 + sx + 2] = t1;
        float2* od = &Os[sj * 64 + so];
        *(float4*)(od)     = o0;
        *(float4*)(od + 2) = o1;
        *(float4*)(od + 4) = o2;
        *(float4*)(od + 6) = o3;
        __syncthreads();

        #pragma unroll
        for (int jj = 0; jj < 32; ++jj) {
            float4 tp = *(const float4*)&Ts[jj * 32 + xr * 2];
            float2 q0 = Os[jj * 64 + or_];
            float2 q1 = Os[jj * 64 + or_ + 16];
            float2 q2 = Os[jj * 64 + or_ + 32];
            float2 q3 = Os[jj * 64 + or_ + 48];
            const int pa = jj & 1;     // constant after unroll
            cmac(acc[pa][0][0], tp.x, tp.y, q0);
            cmac(acc[pa][0][1], tp.x, tp.y, q1);
            cmac(acc[pa][0][2], tp.x, tp.y, q2);
            cmac(acc[pa][0][3], tp.x, tp.y, q3);
            cmac(acc[pa][1][0], tp.z, tp.w, q0);
            cmac(acc[pa][1][1], tp.z, tp.w, q1);
            cmac(acc[pa][1][2], tp.z, tp.w, q2);
            cmac(acc[pa][1][3], tp.z, tp.w, q3);
        }
    }

    float sc = (ky == 0) ? 0.5f : 1.0f;
    #pragma unroll
    for (int p = 0; p < 2; ++p) {
        int x = xt * 32 + xr * 2 + p;
        float2* alo = A + ((size_t)(b * 256 + x) * 32 + ky) * 64 + or_;
        float2* ahi = A + ((size_t)(b * 256 + x + 128) * 32 + ky) * 64 + or_;
        #pragma unroll
        for (int q = 0; q < 4; ++q) {
            float2 se = acc[0][p][q], so2 = acc[1][p][q];
            alo[16 * q] = make_float2((se.x + so2.x) * sc, (se.y + so2.y) * sc);
            ahi[16 * q] = make_float2((se.x - so2.x) * sc, (se.y - so2.y) * sc);
        }
    }
}

// ---------------------------------------------------------------------------
// K5 (GEMM form): per (b,x):
//   S_pi[p][o] = sum_j T2[pi][j][p] * A'[pi][j][o]   (j = 16m x {re,im}, K=32)
//   out[p][o] = S_0+S_1 ; out[p+128][o] = S_0-S_1    (p in [0,128))
// grid = B*H blocks, 512 threads: o4 = (t&15)*4, pr = t>>4 (p = pr*4+pp).
// ---------------------------------------------------------------------------
__global__ __launch_bounds__(512, 2) void k_inv_y(const float* __restrict__ T2g,
                                                  const float2* __restrict__ A,
                                                  float* __restrict__ out) {
    __shared__ float As[2 * 32 * 68];     // [pi][j][o]+pad   17.4 KB
    __shared__ float T2s[2 * 32 * 132];   // [pi][j][p]+pad   33.8 KB

    int t = threadIdx.x;
    int b = blockIdx.x >> 8;
    int x = blockIdx.x & 255;
    int o4 = (t & 15) * 4;
    int pr = t >> 4;            // 0..31 -> p = pr*4 + pp

    float acc[2][4][4];
    #pragma unroll
    for (int pi = 0; pi < 2; ++pi)
        #pragma unroll
        for (int pp = 0; pp < 4; ++pp)
            #pragma unroll
            for (int k = 0; k < 4; ++k) acc[pi][pp][k] = 0.f;

    // stage A' planar: A[b][x][ky][o] -> As[ky&1][2*(ky>>1)+{re,im}][o]
    {
        int ky = t >> 4;            // 0..31
        int oc = (t & 15) * 4;      // complex col
        const float2* ap = A + (size_t)(b * 256 + x) * 2048 + ky * 64 + oc;
        float4 g0 = *(const float4*)(ap);
        float4 g1 = *(const float4*)(ap + 2);
        int pi = ky & 1, m = ky >> 1;
        float* re = As + ((pi * 32) + 2 * m) * 68 + oc;
        float* im = As + ((pi * 32) + 2 * m + 1) * 68 + oc;
        *(float4*)(re) = make_float4(g0.x, g0.z, g1.x, g1.z);
        *(float4*)(im) = make_float4(g0.y, g0.w, g1.y, g1.w);
    }
    // stage full T2: 8192 floats / 512 threads = 16 floats = 4 float4
    {
        int row = t >> 3;           // 0..63 = pi*32 + j
        int c = (t & 7) * 16;       // 0..112
        const float* tg = T2g + (size_t)row * 128 + c;
        float4 q0 = *(const float4*)(tg);
        float4 q1 = *(const float4*)(tg + 4);
        float4 q2 = *(const float4*)(tg + 8);
        float4 q3 = *(const float4*)(tg + 12);
        float* td = T2s + row * 132 + c;
        *(float4*)(td)      = q0;
        *(float4*)(td + 4)  = q1;
        *(float4*)(td + 8)  = q2;
        *(float4*)(td + 12) = q3;
    }
    __syncthreads();

    #pragma unroll
    for (int pi = 0; pi < 2; ++pi) {
        #pragma unroll
        for (int jj = 0; jj < 32; ++jj) {
            float4 ta = *(const float4*)(T2s + (pi * 32 + jj) * 132 + pr * 4);
            float4 av = *(const float4*)(As + (pi * 32 + jj) * 68 + o4);
            acc[pi][0][0] += ta.x * av.x;  acc[pi][0][1] += ta.x * av.y;
            acc[pi][0][2] += ta.x * av.z;  acc[pi][0][3] += ta.x * av.w;
            acc[pi][1][0] += ta.y * av.x;  acc[pi][1][1] += ta.y * av.y;
            acc[pi][1][2] += ta.y * av.z;  acc[pi][1][3] += ta.y * av.w;
            acc[pi][2][0] += ta.z * av.x;  acc[pi][2][1] += ta.z * av.y;
            acc[pi][2][2] += ta.z * av.z;  acc[pi][2][3] += ta.z * av.w;
            acc[pi][3][0] += ta.w * av.x;  acc[pi][3][1] += ta.w * av.y;
            acc[pi][3][2] += ta.w * av.z;  acc[pi][3][3] += ta.w * av.w;
        }
    }

    float* op = out + (size_t)(b * 256 + x) * (256 * 64);
    #pragma unroll
    for (int pp = 0; pp < 4; ++pp) {
        int p = pr * 4 + pp;
        float4 lo = make_float4(acc[0][pp][0] + acc[1][pp][0],
                                acc[0][pp][1] + acc[1][pp][1],
                                acc[0][pp][2] + acc[1][pp][2],
                                acc[0][pp][3] + acc[1][pp][3]);
        float4 hi = make_float4(acc[0][pp][0] - acc[1][pp][0],
                                acc[0][pp][1] - acc[1][pp][1],
                                acc[0][pp][2] - acc[1][pp][2],
                                acc[0][pp][3] - acc[1][pp][3]);
        *(float4*)(op + (size_t)p * 64 + o4)         = lo;
        *(float4*)(op + (size_t)(p + 128) * 64 + o4) = hi;
    }
}

// ---------------------------------------------------------------------------
extern "C" void kernel_launch(void* const* d_in, const int* in_sizes, int n_in,
                              void* d_out, int out_size, void* d_ws, size_t ws_size,
                              hipStream_t stream) {
    const float* u   = (const float*)d_in[0];
    const float* wpr = (const float*)d_in[1];
    const float* wpi = (const float*)d_in[2];
    const float* wnr = (const float*)d_in[3];
    const float* wni = (const float*)d_in[4];
    float* out = (float*)d_out;

    char* ws = (char*)d_ws;
    // U : 64*32*8*64  float2 =  8 MiB  @ 0
    // OF:  8*32*64*64 float2 =  8 MiB  @ 8 MiB
    // V : 8*256*32*64 float2 = 32 MiB  @ 16 MiB (A aliases V)
    // Tf: 128 KiB @ 48 MiB; Ti: 128 KiB; Ty: 32 KiB; T2: 32 KiB
    float2* U  = (float2*)(ws);
    float2* OF = (float2*)(ws + 8388608);
    float2* V  = (float2*)(ws + 16777216);
    float2* A  = V;
    float2* Tf = (float2*)(ws + 50331648);
    float2* Ti = (float2*)(ws + 50331648 + 131072);
    float*  Ty = (float*)(ws + 50331648 + 262144);
    float*  T2 = (float*)(ws + 50331648 + 262144 + 32768);

    k_tw<<<128, 256, 0, stream>>>(Tf, Ti, Ty, T2);
    k_fwd_y<<<BB * HH, 128, 0, stream>>>(u, Ty, V);
    k_fwd_x<<<1024, 256, 0, stream>>>(Tf, V, U);
    k_modew<<<512, 256, 0, stream>>>(wpr, wpi, wnr, wni, U, OF);
    k_inv_x<<<1024, 256, 0, stream>>>(Ti, OF, A);
    k_inv_y<<<BB * HH, 512, 0, stream>>>(T2, A, out);
}

// Round 9
// 224.077 us; speedup vs baseline: 1.2142x; 1.0404x over previous
//
#include <hip/hip_runtime.h>
#include <math.h>

// Sizes fixed by the problem.
#define BB 8
#define HH 256
#define WW 256
#define CC 64
// modes: kx in {0..31} u {224..255} (64 total), ky in {0..31}

__device__ inline void cmac(float2& a, float tx, float ty, float2 v) {
    a.x += tx * v.x - ty * v.y;
    a.y += tx * v.y + ty * v.x;
}
__device__ inline void fma4(float4& a, float s, float4 v) {
    a.x += s * v.x; a.y += s * v.y; a.z += s * v.z; a.w += s * v.w;
}

// ---------------------------------------------------------------------------
// K0: all twiddle tables (one kernel, 128 blocks x 256).
// Tf[x][j]  = e^{-2pi i kxa(j) x/256}                       (fwd x-DFT)
// Ti[j][x]  = (2/65536) e^{+2pi i kxa(j) x/256}             (inv x-DFT)
// Ty[y'][par*32+cs*16+m]: cs=0 -> cos(2pi ky y'/256), cs=1 -> -sin(...),
//                         ky = 2m+par                        (fwd y-DFT)
// T2[(pi*32+j)*128+p]: j=2m+ri; ri=0 -> cos(2pi ky p/256), ri=1 -> -sin(...),
//                         ky = 2m+pi                         (inv y-DFT)
// kxa(j) = j (j<32) else j+192.  parity(kxa(j)) == parity(j).
// ---------------------------------------------------------------------------
__global__ __launch_bounds__(256) void k_tw(float2* __restrict__ Tf,
                                            float2* __restrict__ Ti,
                                            float* __restrict__ Ty,
                                            float* __restrict__ T2) {
    int e = blockIdx.x * 256 + threadIdx.x;   // 0..32767
    if (e < 16384) {
        int x = e >> 6;
        int j = e & 63;
        int kxa = j + ((j >> 5) * 192);
        int tt = (kxa * x) & 255;
        float ang = (float)tt * (6.283185307179586f / 256.0f);
        float s, c;
        sincosf(ang, &s, &c);
        Tf[(size_t)x * 64 + j] = make_float2(c, -s);
        const float k = 2.0f / 65536.0f;
        Ti[(size_t)j * 256 + x] = make_float2(c * k, s * k);
    } else {
        int f = e - 16384;
        if (f < 8192) {
            int yp = f >> 6;
            int col = f & 63;
            int par = (col >> 5) & 1;
            int cs = (col >> 4) & 1;
            int m = col & 15;
            int ky = 2 * m + par;
            int tt = (ky * yp) & 255;
            float ang = (float)tt * (6.283185307179586f / 256.0f);
            float s, c;
            sincosf(ang, &s, &c);
            Ty[f] = cs ? -s : c;
        } else {
            int g = f - 8192;
            int pi = g >> 12;
            int j = (g >> 7) & 31;
            int p = g & 127;
            int m = j >> 1, ri = j & 1;
            int ky = 2 * m + pi;
            int tt = (ky * p) & 255;
            float ang = (float)tt * (6.283185307179586f / 256.0f);
            float s, c;
            sincosf(ang, &s, &c);
            T2[g] = ri ? -s : c;
        }
    }
}

// ---------------------------------------------------------------------------
// K1 (GEMM form, R_i=8): V[b][x][ky][i] = sum_{y'<128} Ty[y'][ky-col] *
//                 (u[y'] + (-1)^ky u[y'+128])[i]
// grid = B*H (one (b,x) row), 128 threads (2 waves).
// ---------------------------------------------------------------------------
__global__ __launch_bounds__(128, 3) void k_fwd_y(const float* __restrict__ u,
                                                  const float* __restrict__ Ty,
                                                  float2* __restrict__ V) {
    __shared__ float ue[32 * 68];
    __shared__ float uo[32 * 68];
    __shared__ float Tt[32 * 68];

    int t = threadIdx.x;
    int b = blockIdx.x >> 8;
    int x = blockIdx.x & 255;
    int i8 = (t & 7) * 8;
    int w = t >> 3;      // 0..15
    int p = w & 1;
    int kyq = w >> 1;    // 0..7
    int yy = t >> 2;     // 0..31
    int c0 = (t & 3) * 16;

    const float* ub = u + ((size_t)(b * HH + x)) * (WW * CC);
    const float* uplane = p ? uo : ue;

    float4 A0r = {0,0,0,0}, A0i = {0,0,0,0};   // m0, i8+0..3
    float4 B0r = {0,0,0,0}, B0i = {0,0,0,0};   // m0, i8+4..7
    float4 A1r = {0,0,0,0}, A1i = {0,0,0,0};   // m1, i8+0..3
    float4 B1r = {0,0,0,0}, B1i = {0,0,0,0};   // m1, i8+4..7

    for (int yt = 0; yt < 4; ++yt) {
        const float* plo = ub + (size_t)(yt * 32 + yy) * CC + c0;
        const float* phi = plo + 128 * CC;
        float4 l0 = *(const float4*)(plo);
        float4 l1 = *(const float4*)(plo + 4);
        float4 l2 = *(const float4*)(plo + 8);
        float4 l3 = *(const float4*)(plo + 12);
        float4 h0 = *(const float4*)(phi);
        float4 h1 = *(const float4*)(phi + 4);
        float4 h2 = *(const float4*)(phi + 8);
        float4 h3 = *(const float4*)(phi + 12);
        const float* tsrc = Ty + (size_t)(yt * 32 + yy) * 64 + c0;
        float4 t0 = *(const float4*)(tsrc);
        float4 t1 = *(const float4*)(tsrc + 4);
        float4 t2 = *(const float4*)(tsrc + 8);
        float4 t3 = *(const float4*)(tsrc + 12);

        __syncthreads();   // previous tile's LDS reads complete
        int wb = yy * 68 + c0;
        *(float4*)(ue + wb)      = make_float4(l0.x+h0.x, l0.y+h0.y, l0.z+h0.z, l0.w+h0.w);
        *(float4*)(ue + wb + 4)  = make_float4(l1.x+h1.x, l1.y+h1.y, l1.z+h1.z, l1.w+h1.w);
        *(float4*)(ue + wb + 8)  = make_float4(l2.x+h2.x, l2.y+h2.y, l2.z+h2.z, l2.w+h2.w);
        *(float4*)(ue + wb + 12) = make_float4(l3.x+h3.x, l3.y+h3.y, l3.z+h3.z, l3.w+h3.w);
        *(float4*)(uo + wb)      = make_float4(l0.x-h0.x, l0.y-h0.y, l0.z-h0.z, l0.w-h0.w);
        *(float4*)(uo + wb + 4)  = make_float4(l1.x-h1.x, l1.y-h1.y, l1.z-h1.z, l1.w-h1.w);
        *(float4*)(uo + wb + 8)  = make_float4(l2.x-h2.x, l2.y-h2.y, l2.z-h2.z, l2.w-h2.w);
        *(float4*)(uo + wb + 12) = make_float4(l3.x-h3.x, l3.y-h3.y, l3.z-h3.z, l3.w-h3.w);
        *(float4*)(Tt + wb)      = t0;
        *(float4*)(Tt + wb + 4)  = t1;
        *(float4*)(Tt + wb + 8)  = t2;
        *(float4*)(Tt + wb + 12) = t3;
        __syncthreads();

        #pragma unroll
        for (int y2 = 0; y2 < 32; ++y2) {
            const float* tb = Tt + y2 * 68 + p * 32 + kyq * 2;
            float2 cp = *(const float2*)(tb);        // cos  m0,m1
            float2 sp = *(const float2*)(tb + 16);   // -sin m0,m1
            const float* up = uplane + y2 * 68 + i8;
            float4 uq0 = *(const float4*)(up);
            float4 uq1 = *(const float4*)(up + 4);
            fma4(A0r, cp.x, uq0);  fma4(A0i, sp.x, uq0);
            fma4(B0r, cp.x, uq1);  fma4(B0i, sp.x, uq1);
            fma4(A1r, cp.y, uq0);  fma4(A1i, sp.y, uq0);
            fma4(B1r, cp.y, uq1);  fma4(B1i, sp.y, uq1);
        }
    }

    // ky = 2m + p, m = 2kyq + d  ->  ky = 4kyq + 2d + p
    {
        int ky = 4 * kyq + p;
        float2* vp = V + (size_t)(b * HH + x) * 2048 + ky * 64 + i8;
        *(float4*)(vp)     = make_float4(A0r.x, A0i.x, A0r.y, A0i.y);
        *(float4*)(vp + 2) = make_float4(A0r.z, A0i.z, A0r.w, A0i.w);
        *(float4*)(vp + 4) = make_float4(B0r.x, B0i.x, B0r.y, B0i.y);
        *(float4*)(vp + 6) = make_float4(B0r.z, B0i.z, B0r.w, B0i.w);
    }
    {
        int ky = 4 * kyq + 2 + p;
        float2* vp = V + (size_t)(b * HH + x) * 2048 + ky * 64 + i8;
        *(float4*)(vp)     = make_float4(A1r.x, A1i.x, A1r.y, A1i.y);
        *(float4*)(vp + 2) = make_float4(A1r.z, A1i.z, A1r.w, A1i.w);
        *(float4*)(vp + 4) = make_float4(B1r.x, B1i.x, B1r.y, B1i.y);
        *(float4*)(vp + 6) = make_float4(B1r.z, B1i.z, B1r.w, B1i.w);
    }
}

// ---------------------------------------------------------------------------
// K2 (radix-2 GEMM): U[j][ky][b][i] = sum_{x<128} Tf[x][j] *
//                    (V[b][x][ky][i] + (-1)^j V[b][x+128][ky][i])
// grid = 1024: bx = jq*256 + (ky + 32*b). The 4 jq-siblings share the same
// V slab; 256 apart -> SAME XCD (256%8==0) -> L2-shared, V fetched once.
// ---------------------------------------------------------------------------
__global__ __launch_bounds__(256) void k_fwd_x(const float2* __restrict__ Tf,
                                               const float2* __restrict__ V,
                                               float2* __restrict__ U) {
    __shared__ float sRe[2 * 2048];   // [par][xx*64+i] 16 KB
    __shared__ float sIm[2 * 2048];   // 16 KB
    __shared__ float2 Ts[32 * 16];    // [xx][jj] 4 KB

    int bx = blockIdx.x;
    int jq = bx >> 8;          // 0..3
    int ky = bx & 31;
    int b  = (bx >> 5) & 7;
    int t = threadIdx.x;
    int jr = t >> 5;      // 0..7
    int ir = t & 31;      // 0..31

    float2 a00 = {0,0}, a01 = {0,0}, a10 = {0,0}, a11 = {0,0};

    const float2* vb = V + (size_t)b * (HH * 2048) + ky * 64;
    int vrow = t >> 3;          // 0..31
    int vcol = (t & 7) * 8;     // complex index
    int tjj = (t & 7) * 2;      // 0..14
    int parOff = (jr & 1) * 2048;

    for (int x0 = 0; x0 < 128; x0 += 32) {
        const float2* plo = vb + (size_t)(x0 + vrow) * 2048 + vcol;
        const float2* phi = plo + 128 * 2048;
        float4 l0 = *(const float4*)(plo);
        float4 l1 = *(const float4*)(plo + 2);
        float4 l2 = *(const float4*)(plo + 4);
        float4 l3 = *(const float4*)(plo + 6);
        float4 h0 = *(const float4*)(phi);
        float4 h1 = *(const float4*)(phi + 2);
        float4 h2 = *(const float4*)(phi + 4);
        float4 h3 = *(const float4*)(phi + 6);
        float4 tv = *(const float4*)(Tf + (size_t)(x0 + vrow) * 64 + jq * 16 + tjj);

        __syncthreads();   // previous tile's LDS reads complete
        *(float4*)&Ts[vrow * 16 + tjj] = tv;
        int wb = vrow * 64 + vcol;
        *(float4*)(sRe + wb)            = make_float4(l0.x+h0.x, l0.z+h0.z, l1.x+h1.x, l1.z+h1.z);
        *(float4*)(sRe + wb + 4)        = make_float4(l2.x+h2.x, l2.z+h2.z, l3.x+h3.x, l3.z+h3.z);
        *(float4*)(sIm + wb)            = make_float4(l0.y+h0.y, l0.w+h0.w, l1.y+h1.y, l1.w+h1.w);
        *(float4*)(sIm + wb + 4)        = make_float4(l2.y+h2.y, l2.w+h2.w, l3.y+h3.y, l3.w+h3.w);
        *(float4*)(sRe + 2048 + wb)     = make_float4(l0.x-h0.x, l0.z-h0.z, l1.x-h1.x, l1.z-h1.z);
        *(float4*)(sRe + 2048 + wb + 4) = make_float4(l2.x-h2.x, l2.z-h2.z, l3.x-h3.x, l3.z-h3.z);
        *(float4*)(sIm + 2048 + wb)     = make_float4(l0.y-h0.y, l0.w-h0.w, l1.y-h1.y, l1.w-h1.w);
        *(float4*)(sIm + 2048 + wb + 4) = make_float4(l2.y-h2.y, l2.w-h2.w, l3.y-h3.y, l3.w-h3.w);
        __syncthreads();

        #pragma unroll
        for (int xx = 0; xx < 32; ++xx) {
            float2 t0 = Ts[xx * 16 + jr];
            float2 t1 = Ts[xx * 16 + jr + 8];
            const float* re = sRe + parOff + xx * 64;
            const float* im = sIm + parOff + xx * 64;
            float vr0 = re[ir], vr1 = re[ir + 32];
            float vi0 = im[ir], vi1 = im[ir + 32];
            a00.x += t0.x*vr0 - t0.y*vi0;  a00.y += t0.x*vi0 + t0.y*vr0;
            a01.x += t0.x*vr1 - t0.y*vi1;  a01.y += t0.x*vi1 + t0.y*vr1;
            a10.x += t1.x*vr0 - t1.y*vi0;  a10.y += t1.x*vi0 + t1.y*vr0;
            a11.x += t1.x*vr1 - t1.y*vi1;  a11.y += t1.x*vi1 + t1.y*vr1;
        }
    }

    int j0 = jq * 16 + jr;
    float2* u0 = U + ((size_t)(j0 * 32 + ky) * 8 + b) * 64 + ir;
    u0[0]  = a00;
    u0[32] = a01;
    float2* u1 = U + ((size_t)((j0 + 8) * 32 + ky) * 8 + b) * 64 + ir;
    u1[0]  = a10;
    u1[32] = a11;
}

// ---------------------------------------------------------------------------
// K3 (fused weight-transpose + mode mul) — round-5/6 structure (known-fast):
// OF[b][ky][j][o] = sum_i U[j][ky][b][i] * (wr[i,o,kxl,ky], wi[i,o,kxl,ky])
// grid = 1024: bx = j + 64*kyt + 512*oh  (kyt 0..7 -> 4 ky; oh 0..1 -> 32 o).
// kyt/oh siblings are 64/512 apart -> same XCD -> weight lines L2-shared.
// 24 KB LDS -> 6 blocks/CU.
// ---------------------------------------------------------------------------
__global__ __launch_bounds__(256) void k_modew(const float* __restrict__ wpr,
                                               const float* __restrict__ wpi,
                                               const float* __restrict__ wnr,
                                               const float* __restrict__ wni,
                                               const float2* __restrict__ U,
                                               float2* __restrict__ OF) {
    __shared__ float2 uS[4 * 8 * 64];   // [kyr][b][i]    16 KB
    __shared__ float2 wS[4 * 8 * 32];   // [kyr][ir][o32]  8 KB (per i-tile)

    int bx = blockIdx.x;
    int j   = bx & 63;
    int kyt = (bx >> 6) & 7;
    int oh  = bx >> 9;
    int ky0 = kyt * 4;
    int sel = j >> 5, kxl = j & 31;
    const float* sr = sel ? wnr : wpr;
    const float* si = sel ? wni : wpi;
    int tid = threadIdx.x;

    const float2* up = U + (size_t)(j * 32 + ky0) * 512;
    #pragma unroll
    for (int k = 0; k < 8; ++k) uS[tid + 256 * k] = up[tid + 256 * k];

    int o32 = tid & 31;
    int bh  = tid >> 5;
    int irS = tid >> 5;
    int ooS = tid & 31;

    float2 acc[4];
    #pragma unroll
    for (int k = 0; k < 4; ++k) acc[k] = make_float2(0.f, 0.f);

    for (int it = 0; it < 8; ++it) {
        __syncthreads();  // uS ready (it==0) / wS reads of prev tile done
        {
            int ig = it * 8 + irS;
            int og = oh * 32 + ooS;
            size_t base = (((size_t)(ig * 64 + og)) * 32 + kxl) * 32 + ky0;
            float4 r0 = *(const float4*)(sr + base);
            float4 q0 = *(const float4*)(si + base);
            float2* wrow = wS + irS * 32 + ooS;
            wrow[0 * 256] = make_float2(r0.x, q0.x);
            wrow[1 * 256] = make_float2(r0.y, q0.y);
            wrow[2 * 256] = make_float2(r0.z, q0.z);
            wrow[3 * 256] = make_float2(r0.w, q0.w);
        }
        __syncthreads();
        #pragma unroll
        for (int ir = 0; ir < 8; ++ir) {
            int ig = it * 8 + ir;
            #pragma unroll
            for (int ky = 0; ky < 4; ++ky) {
                float2 wv = wS[ky * 256 + ir * 32 + o32];
                float2 uv = uS[ky * 512 + bh * 64 + ig];
                acc[ky].x += uv.x * wv.x - uv.y * wv.y;
                acc[ky].y += uv.x * wv.y + uv.y * wv.x;
            }
        }
    }

    int og = oh * 32 + o32;
    #pragma unroll
    for (int ky = 0; ky < 4; ++ky) {
        OF[((size_t)(bh * 32 + ky0 + ky) * 64 + j) * 64 + og] = acc[ky];
    }
}

// ---------------------------------------------------------------------------
// K4 (radix-2 GEMM): for x<128:
//   Se = sum_{even j} Ti[j][x] OF[b][ky][j][o], So = sum_{odd j} ...
//   A[b][x]     = (Se+So)*sc,  A[b][x+128] = (Se-So)*sc   (sc: ky==0 -> 0.5)
// grid = 1024: bx = xt*256 + (ky + 32*b). The 4 xt-siblings share the same
// OF slab; 256 apart -> same XCD -> L2-shared.
// ---------------------------------------------------------------------------
__global__ __launch_bounds__(256) void k_inv_x(const float2* __restrict__ Ti,
                                               const float2* __restrict__ OF,
                                               float2* __restrict__ A) {
    __shared__ float2 Ts[32 * 32];   // [jj][xp]  8 KB
    __shared__ float2 Os[32 * 64];   // [jj][o]  16 KB

    int bx = blockIdx.x;
    int xt = bx >> 8;          // 0..3
    int ky = bx & 31;
    int b  = (bx >> 5) & 7;
    int t = threadIdx.x;
    int or_ = t & 15;
    int xr = t >> 4;     // 0..15

    float2 acc[2][2][4];   // [parity][p][q]
    #pragma unroll
    for (int pa = 0; pa < 2; ++pa)
        #pragma unroll
        for (int p = 0; p < 2; ++p)
            #pragma unroll
            for (int q = 0; q < 4; ++q) acc[pa][p][q] = make_float2(0.f, 0.f);

    const float2* ofb = OF + (size_t)(b * 32 + ky) * 4096;
    int sj = t >> 3;         // 0..31
    int sx = (t & 7) * 4;    // Ts cols (4 complex)
    int so = (t & 7) * 8;    // Os cols (8 complex)

    for (int kh = 0; kh < 2; ++kh) {
        const float2* tsrc = Ti + (size_t)(kh * 32 + sj) * 256 + xt * 32 + sx;
        float4 t0 = *(const float4*)(tsrc);
        float4 t1 = *(const float4*)(tsrc + 2);
        const float2* osrc = ofb + (size_t)(kh * 32 + sj) * 64 + so;
        float4 o0 = *(const float4*)(osrc);
        float4 o1 = *(const float4*)(osrc + 2);
        float4 o2 = *(const float4*)(osrc + 4);
        float4 o3 = *(const float4*)(osrc + 6);

        __syncthreads();
        *(float4*)&Ts[sj * 32 + sx]     = t0;
        *(float4*)&Ts[sj * 32 + sx + 2] = t1;
        float2* od = &Os[sj * 64 + so];
        *(float4*)(od)     = o0;
        *(float4*)(od + 2) = o1;
        *(float4*)(od + 4) = o2;
        *(float4*)(od + 6) = o3;
        __syncthreads();

        #pragma unroll
        for (int jj = 0; jj < 32; ++jj) {
            float4 tp = *(const float4*)&Ts[jj * 32 + xr * 2];
            float2 q0 = Os[jj * 64 + or_];
            float2 q1 = Os[jj * 64 + or_ + 16];
            float2 q2 = Os[jj * 64 + or_ + 32];
            float2 q3 = Os[jj * 64 + or_ + 48];
            const int pa = jj & 1;     // constant after unroll
            cmac(acc[pa][0][0], tp.x, tp.y, q0);
            cmac(acc[pa][0][1], tp.x, tp.y, q1);
            cmac(acc[pa][0][2], tp.x, tp.y, q2);
            cmac(acc[pa][0][3], tp.x, tp.y, q3);
            cmac(acc[pa][1][0], tp.z, tp.w, q0);
            cmac(acc[pa][1][1], tp.z, tp.w, q1);
            cmac(acc[pa][1][2], tp.z, tp.w, q2);
            cmac(acc[pa][1][3], tp.z, tp.w, q3);
        }
    }

    float sc = (ky == 0) ? 0.5f : 1.0f;
    #pragma unroll
    for (int p = 0; p < 2; ++p) {
        int x = xt * 32 + xr * 2 + p;
        float2* alo = A + ((size_t)(b * 256 + x) * 32 + ky) * 64 + or_;
        float2* ahi = A + ((size_t)(b * 256 + x + 128) * 32 + ky) * 64 + or_;
        #pragma unroll
        for (int q = 0; q < 4; ++q) {
            float2 se = acc[0][p][q], so2 = acc[1][p][q];
            alo[16 * q] = make_float2((se.x + so2.x) * sc, (se.y + so2.y) * sc);
            ahi[16 * q] = make_float2((se.x - so2.x) * sc, (se.y - so2.y) * sc);
        }
    }
}

// ---------------------------------------------------------------------------
// K5 (GEMM form): per (b,x):
//   S_pi[p][o] = sum_j T2[pi][j][p] * A'[pi][j][o]   (j = 16m x {re,im}, K=32)
//   out[p][o] = S_0+S_1 ; out[p+128][o] = S_0-S_1    (p in [0,128))
// grid = B*H blocks, 512 threads: o4 = (t&15)*4, pr = t>>4 (p = pr*4+pp).
// ---------------------------------------------------------------------------
__global__ __launch_bounds__(512, 2) void k_inv_y(const float* __restrict__ T2g,
                                                  const float2* __restrict__ A,
                                                  float* __restrict__ out) {
    __shared__ float As[2 * 32 * 68];     // [pi][j][o]+pad   17.4 KB
    __shared__ float T2s[2 * 32 * 132];   // [pi][j][p]+pad   33.8 KB

    int t = threadIdx.x;
    int b = blockIdx.x >> 8;
    int x = blockIdx.x & 255;
    int o4 = (t & 15) * 4;
    int pr = t >> 4;            // 0..31 -> p = pr*4 + pp

    float acc[2][4][4];
    #pragma unroll
    for (int pi = 0; pi < 2; ++pi)
        #pragma unroll
        for (int pp = 0; pp < 4; ++pp)
            #pragma unroll
            for (int k = 0; k < 4; ++k) acc[pi][pp][k] = 0.f;

    // stage A' planar: A[b][x][ky][o] -> As[ky&1][2*(ky>>1)+{re,im}][o]
    {
        int ky = t >> 4;            // 0..31
        int oc = (t & 15) * 4;      // complex col
        const float2* ap = A + (size_t)(b * 256 + x) * 2048 + ky * 64 + oc;
        float4 g0 = *(const float4*)(ap);
        float4 g1 = *(const float4*)(ap + 2);
        int pi = ky & 1, m = ky >> 1;
        float* re = As + ((pi * 32) + 2 * m) * 68 + oc;
        float* im = As + ((pi * 32) + 2 * m + 1) * 68 + oc;
        *(float4*)(re) = make_float4(g0.x, g0.z, g1.x, g1.z);
        *(float4*)(im) = make_float4(g0.y, g0.w, g1.y, g1.w);
    }
    // stage full T2: 8192 floats / 512 threads = 16 floats = 4 float4
    {
        int row = t >> 3;           // 0..63 = pi*32 + j
        int c = (t & 7) * 16;       // 0..112
        const float* tg = T2g + (size_t)row * 128 + c;
        float4 q0 = *(const float4*)(tg);
        float4 q1 = *(const float4*)(tg + 4);
        float4 q2 = *(const float4*)(tg + 8);
        float4 q3 = *(const float4*)(tg + 12);
        float* td = T2s + row * 132 + c;
        *(float4*)(td)      = q0;
        *(float4*)(td + 4)  = q1;
        *(float4*)(td + 8)  = q2;
        *(float4*)(td + 12) = q3;
    }
    __syncthreads();

    #pragma unroll
    for (int pi = 0; pi < 2; ++pi) {
        #pragma unroll
        for (int jj = 0; jj < 32; ++jj) {
            float4 ta = *(const float4*)(T2s + (pi * 32 + jj) * 132 + pr * 4);
            float4 av = *(const float4*)(As + (pi * 32 + jj) * 68 + o4);
            acc[pi][0][0] += ta.x * av.x;  acc[pi][0][1] += ta.x * av.y;
            acc[pi][0][2] += ta.x * av.z;  acc[pi][0][3] += ta.x * av.w;
            acc[pi][1][0] += ta.y * av.x;  acc[pi][1][1] += ta.y * av.y;
            acc[pi][1][2] += ta.y * av.z;  acc[pi][1][3] += ta.y * av.w;
            acc[pi][2][0] += ta.z * av.x;  acc[pi][2][1] += ta.z * av.y;
            acc[pi][2][2] += ta.z * av.z;  acc[pi][2][3] += ta.z * av.w;
            acc[pi][3][0] += ta.w * av.x;  acc[pi][3][1] += ta.w * av.y;
            acc[pi][3][2] += ta.w * av.z;  acc[pi][3][3] += ta.w * av.w;
        }
    }

    float* op = out + (size_t)(b * 256 + x) * (256 * 64);
    #pragma unroll
    for (int pp = 0; pp < 4; ++pp) {
        int p = pr * 4 + pp;
        float4 lo = make_float4(acc[0][pp][0] + acc[1][pp][0],
                                acc[0][pp][1] + acc[1][pp][1],
                                acc[0][pp][2] + acc[1][pp][2],
                                acc[0][pp][3] + acc[1][pp][3]);
        float4 hi = make_float4(acc[0][pp][0] - acc[1][pp][0],
                                acc[0][pp][1] - acc[1][pp][1],
                                acc[0][pp][2] - acc[1][pp][2],
                                acc[0][pp][3] - acc[1][pp][3]);
        *(float4*)(op + (size_t)p * 64 + o4)         = lo;
        *(float4*)(op + (size_t)(p + 128) * 64 + o4) = hi;
    }
}

// ---------------------------------------------------------------------------
extern "C" void kernel_launch(void* const* d_in, const int* in_sizes, int n_in,
                              void* d_out, int out_size, void* d_ws, size_t ws_size,
                              hipStream_t stream) {
    const float* u   = (const float*)d_in[0];
    const float* wpr = (const float*)d_in[1];
    const float* wpi = (const float*)d_in[2];
    const float* wnr = (const float*)d_in[3];
    const float* wni = (const float*)d_in[4];
    float* out = (float*)d_out;

    char* ws = (char*)d_ws;
    // U : 64*32*8*64  float2 =  8 MiB  @ 0
    // OF:  8*32*64*64 float2 =  8 MiB  @ 8 MiB
    // V : 8*256*32*64 float2 = 32 MiB  @ 16 MiB (A aliases V)
    // Tf: 128 KiB @ 48 MiB; Ti: 128 KiB; Ty: 32 KiB; T2: 32 KiB
    float2* U  = (float2*)(ws);
    float2* OF = (float2*)(ws + 8388608);
    float2* V  = (float2*)(ws + 16777216);
    float2* A  = V;
    float2* Tf = (float2*)(ws + 50331648);
    float2* Ti = (float2*)(ws + 50331648 + 131072);
    float*  Ty = (float*)(ws + 50331648 + 262144);
    float*  T2 = (float*)(ws + 50331648 + 262144 + 32768);

    k_tw<<<128, 256, 0, stream>>>(Tf, Ti, Ty, T2);
    k_fwd_y<<<BB * HH, 128, 0, stream>>>(u, Ty, V);
    k_fwd_x<<<1024, 256, 0, stream>>>(Tf, V, U);
    k_modew<<<1024, 256, 0, stream>>>(wpr, wpi, wnr, wni, U, OF);
    k_inv_x<<<1024, 256, 0, stream>>>(Ti, OF, A);
    k_inv_y<<<BB * HH, 512, 0, stream>>>(T2, A, out);
}